// Round 1
// baseline (417.472 us; speedup 1.0000x reference)
//
#include <hip/hip_runtime.h>
#include <hip/hip_bf16.h>
#include <stdint.h>

// Problem constants (B=32, T=512, C=16, F=256, O=256)
#define R_TOTAL 16384   // B*T rows
#define F_DIM 256
#define C_DIM 16
#define O_DIM 256
#define K_DIM 768       // 3*F
#define ROWS_PB 16      // rows per block (fused kernel) — 16 => grid 1024, ~27KB LDS
#define MIX_STRIDE 792  // 768 + 24 pad: row stride = 1584B = 396 words ≡ 12 mod 32
                        // -> A-frag ds_read_b128 rows alias only 2-way (free, m136)

using bf16x8 = __attribute__((ext_vector_type(8))) short;
using f32x4  = __attribute__((ext_vector_type(4))) float;

// RNE float->bf16 (inputs finite; no NaN path needed)
__device__ __forceinline__ unsigned short f2bf(float x) {
    union { float f; unsigned u; } a; a.f = x;
    unsigned r = a.u + 0x7FFFu + ((a.u >> 16) & 1u);
    return (unsigned short)(r >> 16);
}

// ---------------------------------------------------------------------------
// Kernel 1: weights -> concatenated transposed bf16 Wt[n=256][k=768]
// k blocks: 0:w_t, 1:w_r, 2:w_l (reference stacks [w_t, w_r, w_l]).
// Tiny (384 KB out); stays L2-resident for the fused kernel's B-frag loads.
// ---------------------------------------------------------------------------
__global__ __launch_bounds__(256) void wconv_kernel(
    const float* __restrict__ w_t, const float* __restrict__ w_l,
    const float* __restrict__ w_r, unsigned short* __restrict__ Wt)
{
    const int n = blockIdx.x;    // 0..255 output col
    const int t = threadIdx.x;   // 0..255 k within a 256-block
    unsigned short* dst = Wt + (size_t)n * K_DIM;
    dst[t]       = f2bf(w_t[(size_t)t * O_DIM + n]);
    dst[256 + t] = f2bf(w_r[(size_t)t * O_DIM + n]);
    dst[512 + t] = f2bf(w_l[(size_t)t * O_DIM + n]);
}

// ---------------------------------------------------------------------------
// Kernel 2 (fused): per-row coefficients + child mixing -> LDS, then MFMA
// GEMM against L2-resident Wt, bias + leaky_relu epilogue.
// Block = 16 rows, 256 threads (4 waves). Wave w owns output cols [w*64,w*64+64).
// Grid = 1024 blocks -> 4+ resident blocks/CU (LDS ~27KB, launch_bounds(256,4))
// so one block's stage-1 HBM burst overlaps another's stage-2 MFMA.
// ---------------------------------------------------------------------------
__global__ __launch_bounds__(256, 4) void fused_kernel(
    const float* __restrict__ nodes,      // [R,256]
    const float* __restrict__ cv,         // [R,16,256]
    const int*   __restrict__ children,   // [R,16]
    const unsigned short* __restrict__ Wt,// [256,768] bf16
    const float* __restrict__ conv,       // [256]
    float* __restrict__ out)              // [R,256]
{
    __shared__ unsigned short mixed[ROWS_PB * MIX_STRIDE];  // ~25.3 KB
    __shared__ float cr_s[ROWS_PB][C_DIM];                  // 1 KB
    __shared__ float cl_s[ROWS_PB][C_DIM];                  // 1 KB

    const int tid  = threadIdx.x;
    const int lane = tid & 63;
    const int wave = tid >> 6;
    const int row0 = blockIdx.x * ROWS_PB;

    // --- coefficients: one thread per row (16 active threads) ---
    if (tid < ROWS_PB) {
        const int* chp = children + (size_t)(row0 + tid) * C_DIM;
        unsigned mask = 0;
#pragma unroll
        for (int i = 0; i < C_DIM; ++i)
            mask |= (chp[i] != 0) ? (1u << i) : 0u;
        const int ns = __popc(mask);
        if (ns == 1) {
            // reference "singles": c_r = 0.5 on first child slot, UNmasked
#pragma unroll
            for (int i = 0; i < C_DIM; ++i) {
                float m  = (float)((mask >> i) & 1u);
                float cr = (i == 0) ? 0.5f : 0.0f;
                cr_s[tid][i] = cr;
                cl_s[tid][i] = (1.0f - cr) * m;
            }
        } else {
            float inv = (ns > 1) ? 1.0f / (float)(ns - 1) : 0.0f;  // ns==0: masks all 0
#pragma unroll
            for (int i = 0; i < C_DIM; ++i) {
                float m  = (float)((mask >> i) & 1u);
                float cr = (float)i * m * inv;
                cr_s[tid][i] = cr;
                cl_s[tid][i] = (1.0f - cr) * m;
            }
        }
    }
    __syncthreads();

    // --- stage 1: mix children vectors -> mixed[16][768] bf16 in LDS ---
    // wave w handles rows w*4 .. w*4+3; each lane owns 4 consecutive features.
    for (int j = 0; j < ROWS_PB / 4; ++j) {
        const int lr  = wave * (ROWS_PB / 4) + j;
        const int row = row0 + lr;
        float crr[C_DIM], cll[C_DIM];
#pragma unroll
        for (int i = 0; i < C_DIM; ++i) { crr[i] = cr_s[lr][i]; cll[i] = cl_s[lr][i]; }

        const float4* cvp = (const float4*)(cv + (size_t)row * (C_DIM * F_DIM));
        float4 mr = make_float4(0.f, 0.f, 0.f, 0.f);
        float4 ml = make_float4(0.f, 0.f, 0.f, 0.f);
#pragma unroll
        for (int i = 0; i < C_DIM; ++i) {
            float4 v = cvp[i * 64 + lane];
            float cr = crr[i], cl = cll[i];
            mr.x = fmaf(v.x, cr, mr.x); mr.y = fmaf(v.y, cr, mr.y);
            mr.z = fmaf(v.z, cr, mr.z); mr.w = fmaf(v.w, cr, mr.w);
            ml.x = fmaf(v.x, cl, ml.x); ml.y = fmaf(v.y, cl, ml.y);
            ml.z = fmaf(v.z, cl, ml.z); ml.w = fmaf(v.w, cl, ml.w);
        }
        float4 mt = ((const float4*)(nodes + (size_t)row * F_DIM))[lane];

        ushort4 ut = { f2bf(mt.x), f2bf(mt.y), f2bf(mt.z), f2bf(mt.w) };
        ushort4 ur = { f2bf(mr.x), f2bf(mr.y), f2bf(mr.z), f2bf(mr.w) };
        ushort4 ul = { f2bf(ml.x), f2bf(ml.y), f2bf(ml.z), f2bf(ml.w) };

        ushort4* mrow = (ushort4*)&mixed[lr * MIX_STRIDE];
        mrow[lane]       = ut;   // k = 4*lane          (w_t block)
        mrow[64 + lane]  = ur;   // k = 256 + 4*lane    (w_r block)
        mrow[128 + lane] = ul;   // k = 512 + 4*lane    (w_l block)
    }
    __syncthreads();

    // --- stage 2: GEMM [16 x 768] x Wt^T -> [16 x 256], wave w: cols w*64.. ---
    f32x4 acc[4] = {};
    const int fr  = lane & 15;          // frag row (A: m, B: n)
    const int fkd = (lane >> 4) * 8;    // frag k element offset
    const unsigned short* bptr = Wt + (size_t)(wave * 64 + fr) * K_DIM + fkd;
    const unsigned short* aptr = &mixed[fr * MIX_STRIDE + fkd];

    for (int k0 = 0; k0 < K_DIM; k0 += 32) {
        bf16x8 bfrag[4];
#pragma unroll
        for (int ni = 0; ni < 4; ++ni)
            bfrag[ni] = *(const bf16x8*)(bptr + (size_t)ni * 16 * K_DIM + k0);
        bf16x8 afrag = *(const bf16x8*)(aptr + k0);
#pragma unroll
        for (int ni = 0; ni < 4; ++ni)
            acc[ni] = __builtin_amdgcn_mfma_f32_16x16x32_bf16(
                afrag, bfrag[ni], acc[ni], 0, 0, 0);
    }

    // --- epilogue: +conv, leaky_relu(0.01), fp32 out ---
    // C/D layout: col = lane&15, row = (lane>>4)*4 + reg   [m89/m91]
    const int cn    = lane & 15;
    const int rbase = (lane >> 4) * 4;
#pragma unroll
    for (int ni = 0; ni < 4; ++ni) {
        const int ncol = wave * 64 + ni * 16 + cn;
        const float cb = conv[ncol];
        float* op = out + (size_t)(row0 + rbase) * O_DIM + ncol;
#pragma unroll
        for (int r = 0; r < 4; ++r) {
            float v = acc[ni][r] + cb;
            op[(size_t)r * O_DIM] = (v > 0.0f) ? v : 0.01f * v;
        }
    }
}

// ---------------------------------------------------------------------------
extern "C" void kernel_launch(void* const* d_in, const int* in_sizes, int n_in,
                              void* d_out, int out_size, void* d_ws, size_t ws_size,
                              hipStream_t stream) {
    // setup_inputs order: nodes, children_vectors, w_t, w_l, w_r, conv, children
    const float* nodes    = (const float*)d_in[0];
    const float* cv       = (const float*)d_in[1];
    const float* w_t      = (const float*)d_in[2];
    const float* w_l      = (const float*)d_in[3];
    const float* w_r      = (const float*)d_in[4];
    const float* conv     = (const float*)d_in[5];
    const int*   children = (const int*)d_in[6];
    float* out = (float*)d_out;

    unsigned short* Wt = (unsigned short*)d_ws;   // 384 KB bf16

    wconv_kernel<<<dim3(O_DIM), dim3(256), 0, stream>>>(w_t, w_l, w_r, Wt);
    fused_kernel<<<dim3(R_TOTAL / ROWS_PB), dim3(256), 0, stream>>>(
        nodes, cv, children, Wt, conv, out);
}